// Round 5
// baseline (49.286 us; speedup 1.0000x reference)
//
#include <hip/hip_runtime.h>

// Daubechies-4 (db2) synthesis filter taps, f32
#define H_0 0.48296291314469025f
#define H_1 0.8365163037378079f
#define H_2 0.22414386804201336f
#define H_3 (-0.12940952255092145f)
#define G_0 (-0.12940952255092145f)
#define G_1 (-0.22414386804201336f)
#define G_2 0.8365163037378079f
#define G_3 (-0.48296291314469025f)

// Register-only fused one-level inverse db2: no LDS, no barriers.
// One wave owns a 2-row x 512-col output patch. Lane l holds t (row-pass
// result) for t-rows {2m, 2m+1} at 4 low cols [cl, cl+4) and 4 high cols
// [S2+cl, S2+cl+4). Col-pass neighbor t[n-1] for the lane's first column
// comes from the previous lane via __shfl_up; lane 0 recomputes the
// wave-left t column from 8 wave-uniform (broadcast) scalar loads.

__device__ __forceinline__ float4 rowpass4(float h0, float h2, float g0, float g2,
                                           const float4& P, const float4& Q,
                                           const float4& R, const float4& T) {
    return make_float4(h0 * P.x + h2 * Q.x + g0 * R.x + g2 * T.x,
                       h0 * P.y + h2 * Q.y + g0 * R.y + g2 * T.y,
                       h0 * P.z + h2 * Q.z + g0 * R.z + g2 * T.z,
                       h0 * P.w + h2 * Q.w + g0 * R.w + g2 * T.w);
}

// Col-pass for one output row: 8 consecutive outputs from t-low L (4 cols),
// t-high Hi (4 cols), and the left neighbors Lm1/Hm1 (scalar).
__device__ __forceinline__ void colpass_store(float* __restrict__ dst,
                                              const float4 L, const float Lm1,
                                              const float4 Hi, const float Hm1) {
    float4 s0, s1;
    s0.x = H_0 * L.x + H_2 * Lm1 + G_0 * Hi.x + G_2 * Hm1;
    s0.y = H_1 * L.x + H_3 * Lm1 + G_1 * Hi.x + G_3 * Hm1;
    s0.z = H_0 * L.y + H_2 * L.x + G_0 * Hi.y + G_2 * Hi.x;
    s0.w = H_1 * L.y + H_3 * L.x + G_1 * Hi.y + G_3 * Hi.x;
    s1.x = H_0 * L.z + H_2 * L.y + G_0 * Hi.z + G_2 * Hi.y;
    s1.y = H_1 * L.z + H_3 * L.y + G_1 * Hi.z + G_3 * Hi.y;
    s1.z = H_0 * L.w + H_2 * L.z + G_0 * Hi.w + G_2 * Hi.z;
    s1.w = H_1 * L.w + H_3 * L.z + G_1 * Hi.w + G_3 * Hi.z;
    *reinterpret_cast<float4*>(dst) = s0;
    *reinterpret_cast<float4*>(dst + 4) = s1;
}

__global__ __launch_bounds__(256) void iwt_fused_reg(
    const float* __restrict__ x, int ldx,
    const float* __restrict__ sub, int ldsub,
    float* __restrict__ out, int ldo,
    int S2, int segShift) {
    const int lane = threadIdx.x & 63;
    const int wid = (blockIdx.x * 256 + threadIdx.x) >> 6;   // global wave id
    const int seg = wid & ((1 << segShift) - 1);             // 256-col segment
    const int m = wid >> segShift;                           // row-pass strip
    const int mp = (m == 0) ? (S2 - 1) : (m - 1);
    const int cl = (seg << 8) + (lane << 2);                 // lane's low t-col
    int lw = (seg << 8) - 1;                                 // wave-left t-col
    if (lw < 0) lw = S2 - 1;                                 // circular wrap

    const bool hasSub = (sub != nullptr);
    const float* __restrict__ pA = hasSub ? sub : x;         // rows<S2, cols<S2
    const int ldA = hasSub ? ldsub : ldx;

    // 8 coalesced float4 loads (1 KB/wave each).
    const float4 A0 = *reinterpret_cast<const float4*>(pA + (size_t)m  * ldA + cl);
    const float4 A1 = *reinterpret_cast<const float4*>(pA + (size_t)mp * ldA + cl);
    const float4 B0 = *reinterpret_cast<const float4*>(x + (size_t)(S2 + m)  * ldx + cl);
    const float4 B1 = *reinterpret_cast<const float4*>(x + (size_t)(S2 + mp) * ldx + cl);
    const float4 C0 = *reinterpret_cast<const float4*>(x + (size_t)m  * ldx + S2 + cl);
    const float4 C1 = *reinterpret_cast<const float4*>(x + (size_t)mp * ldx + S2 + cl);
    const float4 D0 = *reinterpret_cast<const float4*>(x + (size_t)(S2 + m)  * ldx + S2 + cl);
    const float4 D1 = *reinterpret_cast<const float4*>(x + (size_t)(S2 + mp) * ldx + S2 + cl);

    // Wave-uniform broadcast loads for the wave-left t column (lane 0's n-1).
    const float a0 = pA[(size_t)m  * ldA + lw];
    const float a1 = pA[(size_t)mp * ldA + lw];
    const float b0 = x[(size_t)(S2 + m)  * ldx + lw];
    const float b1 = x[(size_t)(S2 + mp) * ldx + lw];
    const float c0 = x[(size_t)m  * ldx + S2 + lw];
    const float c1 = x[(size_t)mp * ldx + S2 + lw];
    const float d0 = x[(size_t)(S2 + m)  * ldx + S2 + lw];
    const float d1 = x[(size_t)(S2 + mp) * ldx + S2 + lw];

    // Row pass -> t for rows {2m, 2m+1}, low and high col groups.
    const float4 TL0 = rowpass4(H_0, H_2, G_0, G_2, A0, A1, B0, B1);
    const float4 TL1 = rowpass4(H_1, H_3, G_1, G_3, A0, A1, B0, B1);
    const float4 TH0 = rowpass4(H_0, H_2, G_0, G_2, C0, C1, D0, D1);
    const float4 TH1 = rowpass4(H_1, H_3, G_1, G_3, C0, C1, D0, D1);

    // Wave-left t column (used by lane 0 only).
    const float tl0 = H_0 * a0 + H_2 * a1 + G_0 * b0 + G_2 * b1;
    const float tl1 = H_1 * a0 + H_3 * a1 + G_1 * b0 + G_3 * b1;
    const float th0 = H_0 * c0 + H_2 * c1 + G_0 * d0 + G_2 * d1;
    const float th1 = H_1 * c0 + H_3 * c1 + G_1 * d0 + G_3 * d1;

    // Neighbor t[n-1] for the lane's first column.
    float pL0 = __shfl_up(TL0.w, 1); if (lane == 0) pL0 = tl0;
    float pL1 = __shfl_up(TL1.w, 1); if (lane == 0) pL1 = tl1;
    float pH0 = __shfl_up(TH0.w, 1); if (lane == 0) pH0 = th0;
    float pH1 = __shfl_up(TH1.w, 1); if (lane == 0) pH1 = th1;

    // Col pass + store: rows 2m and 2m+1, cols [2*cl, 2*cl+8).
    float* o0 = out + (size_t)(2 * m) * ldo + 2 * cl;
    colpass_store(o0, TL0, pL0, TH0, pH0);
    colpass_store(o0 + ldo, TL1, pL1, TH1, pH1);
}

extern "C" void kernel_launch(void* const* d_in, const int* in_sizes, int n_in,
                              void* d_out, int out_size, void* d_ws, size_t ws_size,
                              hipStream_t stream) {
    const float* x = (const float*)d_in[0];   // (1, 4096, 4096) f32
    // d_in[1] = mask, d_in[2] = b : unused; d_in[3] = wavSplit -> levels = 3
    float* out = (float*)d_out;               // 4096 x 4096 f32
    float* buf1 = (float*)d_ws;                                 // 1024^2 f32 (4 MB)
    float* buf2 = (float*)((char*)d_ws + ((size_t)16 << 20));   // 2048^2 f32 (16 MB)

    const int N = 4096;

    // waves = S2 * (S2/256); blocks = waves / 4 (4 waves per 256-thread block)
    // Level 1 (S=1024, S2=512, nsegs=2): x top-left, no sub -> buf1 (ld 1024).
    {
        const int S2 = 512, segShift = 1;
        const int blocks = (S2 << segShift) >> 2;
        iwt_fused_reg<<<blocks, 256, 0, stream>>>(x, N, nullptr, 0, buf1, 1024, S2, segShift);
    }
    // Level 2 (S=2048, S2=1024, nsegs=4): sub = buf1 -> buf2 (ld 2048).
    {
        const int S2 = 1024, segShift = 2;
        const int blocks = (S2 << segShift) >> 2;
        iwt_fused_reg<<<blocks, 256, 0, stream>>>(x, N, buf1, 1024, buf2, 2048, S2, segShift);
    }
    // Level 3 (S=4096, S2=2048, nsegs=8): sub = buf2 -> out (ld 4096).
    {
        const int S2 = 2048, segShift = 3;
        const int blocks = (S2 << segShift) >> 2;
        iwt_fused_reg<<<blocks, 256, 0, stream>>>(x, N, buf2, 2048, out, N, S2, segShift);
    }
}

// Round 6
// 43.551 us; speedup vs baseline: 1.1317x; 1.1317x over previous
//
#include <hip/hip_runtime.h>

// Daubechies-4 (db2) synthesis filter taps, f32
#define H_0 0.48296291314469025f
#define H_1 0.8365163037378079f
#define H_2 0.22414386804201336f
#define H_3 (-0.12940952255092145f)
#define G_0 (-0.12940952255092145f)
#define G_1 (-0.22414386804201336f)
#define G_2 0.8365163037378079f
#define G_3 (-0.48296291314469025f)

// Persistent rolling-stream fused inverse db2 level. One wave owns a 256
// t-col segment (lane l -> 4 low cols [cl,cl+4), 4 high cols [S2+cl,..)) and
// walks K consecutive row-pass strips m. Rows {m-1} inputs are carried in
// registers from iteration m-1 (only 4 float4 + 4 broadcast loads per iter).
// Col-pass neighbor t[n-1] comes from the previous lane via __shfl_up; lane 0
// patches from the wave-left t column computed from broadcast scalar loads.

__device__ __forceinline__ float4 rowpass4(float h0, float h2, float g0, float g2,
                                           const float4& P, const float4& Q,
                                           const float4& R, const float4& T) {
    return make_float4(h0 * P.x + h2 * Q.x + g0 * R.x + g2 * T.x,
                       h0 * P.y + h2 * Q.y + g0 * R.y + g2 * T.y,
                       h0 * P.z + h2 * Q.z + g0 * R.z + g2 * T.z,
                       h0 * P.w + h2 * Q.w + g0 * R.w + g2 * T.w);
}

__device__ __forceinline__ void colpass_store(float* __restrict__ dst,
                                              const float4 L, const float Lm1,
                                              const float4 Hi, const float Hm1) {
    float4 s0, s1;
    s0.x = H_0 * L.x + H_2 * Lm1 + G_0 * Hi.x + G_2 * Hm1;
    s0.y = H_1 * L.x + H_3 * Lm1 + G_1 * Hi.x + G_3 * Hm1;
    s0.z = H_0 * L.y + H_2 * L.x + G_0 * Hi.y + G_2 * Hi.x;
    s0.w = H_1 * L.y + H_3 * L.x + G_1 * Hi.y + G_3 * Hi.x;
    s1.x = H_0 * L.z + H_2 * L.y + G_0 * Hi.z + G_2 * Hi.y;
    s1.y = H_1 * L.z + H_3 * L.y + G_1 * Hi.z + G_3 * Hi.y;
    s1.z = H_0 * L.w + H_2 * L.z + G_0 * Hi.w + G_2 * Hi.z;
    s1.w = H_1 * L.w + H_3 * L.z + G_1 * Hi.w + G_3 * Hi.z;
    *reinterpret_cast<float4*>(dst) = s0;
    *reinterpret_cast<float4*>(dst + 4) = s1;
}

__global__ __launch_bounds__(256) void iwt_fused_roll(
    const float* __restrict__ x, int ldx,
    const float* __restrict__ sub, int ldsub,
    float* __restrict__ out, int ldo,
    int S2, int segShift, int K) {
    const int lane = threadIdx.x & 63;
    const int wid = (blockIdx.x * 256 + threadIdx.x) >> 6;   // global wave id
    const int seg = wid & ((1 << segShift) - 1);             // 256-t-col segment
    const int m0 = (wid >> segShift) * K;                    // first strip
    const int cl = (seg << 8) + (lane << 2);                 // lane's low t-col
    int lw = (seg << 8) - 1;                                 // wave-left t-col
    if (lw < 0) lw = S2 - 1;                                 // circular wrap

    const bool hasSub = (sub != nullptr);
    const float* __restrict__ pA = hasSub ? sub : x;         // rows<S2, cols<S2
    const int ldA = hasSub ? ldsub : ldx;

    // Prologue: "previous row" inputs at mp0 (circular wrap only possible here).
    const int mp0 = (m0 == 0) ? (S2 - 1) : (m0 - 1);
    float4 Ap = *reinterpret_cast<const float4*>(pA + (size_t)mp0 * ldA + cl);
    float4 Bp = *reinterpret_cast<const float4*>(x + (size_t)(S2 + mp0) * ldx + cl);
    float4 Cp = *reinterpret_cast<const float4*>(x + (size_t)mp0 * ldx + S2 + cl);
    float4 Dp = *reinterpret_cast<const float4*>(x + (size_t)(S2 + mp0) * ldx + S2 + cl);
    float ap = pA[(size_t)mp0 * ldA + lw];
    float bp = x[(size_t)(S2 + mp0) * ldx + lw];
    float cp = x[(size_t)mp0 * ldx + S2 + lw];
    float dp = x[(size_t)(S2 + mp0) * ldx + S2 + lw];

    for (int i = 0; i < K; ++i) {
        const int m = m0 + i;
        // 4 coalesced float4 loads (rows m, S2+m at low/high col groups).
        const float4 A = *reinterpret_cast<const float4*>(pA + (size_t)m * ldA + cl);
        const float4 B = *reinterpret_cast<const float4*>(x + (size_t)(S2 + m) * ldx + cl);
        const float4 C = *reinterpret_cast<const float4*>(x + (size_t)m * ldx + S2 + cl);
        const float4 D = *reinterpret_cast<const float4*>(x + (size_t)(S2 + m) * ldx + S2 + cl);
        // 4 wave-uniform broadcast loads for the wave-left t column.
        const float a = pA[(size_t)m * ldA + lw];
        const float b = x[(size_t)(S2 + m) * ldx + lw];
        const float c = x[(size_t)m * ldx + S2 + lw];
        const float d = x[(size_t)(S2 + m) * ldx + S2 + lw];

        // Row pass -> t rows {2m, 2m+1}, low and high col groups.
        const float4 TL0 = rowpass4(H_0, H_2, G_0, G_2, A, Ap, B, Bp);
        const float4 TL1 = rowpass4(H_1, H_3, G_1, G_3, A, Ap, B, Bp);
        const float4 TH0 = rowpass4(H_0, H_2, G_0, G_2, C, Cp, D, Dp);
        const float4 TH1 = rowpass4(H_1, H_3, G_1, G_3, C, Cp, D, Dp);

        // Wave-left t column (lane 0's n-1 source).
        const float tl0 = H_0 * a + H_2 * ap + G_0 * b + G_2 * bp;
        const float tl1 = H_1 * a + H_3 * ap + G_1 * b + G_3 * bp;
        const float th0 = H_0 * c + H_2 * cp + G_0 * d + G_2 * dp;
        const float th1 = H_1 * c + H_3 * cp + G_1 * d + G_3 * dp;

        float pL0 = __shfl_up(TL0.w, 1); if (lane == 0) pL0 = tl0;
        float pL1 = __shfl_up(TL1.w, 1); if (lane == 0) pL1 = tl1;
        float pH0 = __shfl_up(TH0.w, 1); if (lane == 0) pH0 = th0;
        float pH1 = __shfl_up(TH1.w, 1); if (lane == 0) pH1 = th1;

        // Col pass + store: rows 2m, 2m+1, cols [2*cl, 2*cl+8).
        float* o0 = out + (size_t)(2 * m) * ldo + 2 * cl;
        colpass_store(o0, TL0, pL0, TH0, pH0);
        colpass_store(o0 + ldo, TL1, pL1, TH1, pH1);

        // Roll: current rows become previous rows.
        Ap = A; Bp = B; Cp = C; Dp = D;
        ap = a; bp = b; cp = c; dp = d;
    }
}

extern "C" void kernel_launch(void* const* d_in, const int* in_sizes, int n_in,
                              void* d_out, int out_size, void* d_ws, size_t ws_size,
                              hipStream_t stream) {
    const float* x = (const float*)d_in[0];   // (1, 4096, 4096) f32
    // d_in[1] = mask, d_in[2] = b : unused; d_in[3] = wavSplit -> levels = 3
    float* out = (float*)d_out;               // 4096 x 4096 f32
    float* buf1 = (float*)d_ws;                                 // 1024^2 f32 (4 MB)
    float* buf2 = (float*)((char*)d_ws + ((size_t)16 << 20));   // 2048^2 f32 (16 MB)

    const int N = 4096;

    // waves = nsegs * S2 / K; blocks = waves / 4.
    // Level 1 (S2=512, nsegs=2, K=1): 1024 waves -> 256 blocks.
    iwt_fused_roll<<<256, 256, 0, stream>>>(x, N, nullptr, 0, buf1, 1024, 512, 1, 1);
    // Level 2 (S2=1024, nsegs=4, K=2): 2048 waves -> 512 blocks.
    iwt_fused_roll<<<512, 256, 0, stream>>>(x, N, buf1, 1024, buf2, 2048, 1024, 2, 2);
    // Level 3 (S2=2048, nsegs=8, K=8): 2048 waves -> 512 blocks.
    iwt_fused_roll<<<512, 256, 0, stream>>>(x, N, buf2, 2048, out, N, 2048, 3, 8);
}